// Round 5
// baseline (32946.844 us; speedup 1.0000x reference)
//
#include <hip/hip_runtime.h>
#include <hip/hip_fp16.h>
#include <math.h>

#define B 64
#define L 128
#define N_ 512
#define E_ 512
#define H_ 512
#define G3 1536
#define NWG 256
#define NEG -1e9f

__device__ __forceinline__ float2 uh2f2(unsigned u) {
  __half2 h;
  __builtin_memcpy(&h, &u, 4);
  return __half22float2(h);
}
__device__ __forceinline__ unsigned f2uh2(float x, float y) {
  __half2 h = __floats2half2_rn(x, y);
  unsigned u;
  __builtin_memcpy(&u, &h, 4);
  return u;
}

// Fast grid barrier: per-WG flag (no contention) + WG0 fan-in + gen broadcast.
// Acquire/release at AGENT scope = cross-XCD safe (same primitives as the
// pair-sync that already validated in R4).
__device__ __forceinline__ void gbar(unsigned* __restrict__ flags,
                                     unsigned* __restrict__ gen,
                                     unsigned epoch) {
  __syncthreads();
  const int tid = threadIdx.x;
  if (blockIdx.x == 0) {
    if (tid >= 1 && tid < NWG) {
      while (__hip_atomic_load(&flags[tid], __ATOMIC_ACQUIRE,
                               __HIP_MEMORY_SCOPE_AGENT) < epoch)
        __builtin_amdgcn_s_sleep(2);
    }
    __syncthreads();
    if (tid == 0)
      __hip_atomic_store(gen, epoch, __ATOMIC_RELEASE,
                         __HIP_MEMORY_SCOPE_AGENT);
  } else {
    if (tid == 0) {
      __hip_atomic_store(&flags[blockIdx.x], epoch, __ATOMIC_RELEASE,
                         __HIP_MEMORY_SCOPE_AGENT);
      while (__hip_atomic_load(gen, __ATOMIC_ACQUIRE,
                               __HIP_MEMORY_SCOPE_AGENT) < epoch)
        __builtin_amdgcn_s_sleep(2);
    }
  }
  __syncthreads();
}

// ---------------- precompute kernels (once per call) ----------------

__global__ __launch_bounds__(512) void k_init(const float* __restrict__ state,
                                              float* __restrict__ h32,
                                              unsigned* __restrict__ h2g,
                                              float* __restrict__ cov,
                                              unsigned* __restrict__ scnt,
                                              unsigned* __restrict__ bflags,
                                              unsigned* __restrict__ bgen) {
  int i = blockIdx.x * 512 + threadIdx.x;  // 0..32767
  int jh = i >> 6, b = i & 63;
  float v = state[b * H_ + jh];
  h32[i] = v;
  ((__half*)h2g)[((size_t)(jh >> 1) * 64 + b) * 2 + (jh & 1)] = __float2half(v);
  cov[i] = 0.f;
  if (i < 64) scnt[i] = 0u;
  if (i < NWG) bflags[i] = 0u;
  if (i == 0) *bgen = 0u;
}

__global__ __launch_bounds__(256) void k_cvt(const float* __restrict__ v,
                                             __half* __restrict__ o) {
  size_t i = ((size_t)blockIdx.x * 256 + threadIdx.x) * 4;
  float4 f = *(const float4*)(v + i);
  __half2* d = (__half2*)(o + i);
  d[0] = __floats2half2_rn(f.x, f.y);
  d[1] = __floats2half2_rn(f.z, f.w);
}

// vk[b,n,k] = sum_h value[b,n,h]*Wk[k,h] + b_attn[k]   (fp16)
__global__ __launch_bounds__(256) void k_vk(const float* __restrict__ value,
                                            const float* __restrict__ Wk,
                                            const float* __restrict__ b_attn,
                                            __half* __restrict__ vk) {
  int k0 = blockIdx.x * 64, n0 = blockIdx.y * 64, b = blockIdx.z;
  int tid = threadIdx.x;
  int tn = tid >> 4, tk = tid & 15;
  __shared__ float Vs[64][33];
  __shared__ float Ws[64][33];
  const float* vb = value + (size_t)b * N_ * H_;
  float acc[4][4] = {};
  for (int h0 = 0; h0 < H_; h0 += 32) {
#pragma unroll
    for (int e = 0; e < 8; ++e) {
      int idx = tid + e * 256;
      int r = idx >> 5, c = idx & 31;
      Vs[r][c] = vb[(size_t)(n0 + r) * H_ + h0 + c];
      Ws[r][c] = Wk[(size_t)(k0 + r) * H_ + h0 + c];
    }
    __syncthreads();
#pragma unroll
    for (int c = 0; c < 32; ++c) {
      float av[4], wv[4];
#pragma unroll
      for (int i = 0; i < 4; ++i) av[i] = Vs[tn * 4 + i][c];
#pragma unroll
      for (int jq = 0; jq < 4; ++jq) wv[jq] = Ws[tk * 4 + jq][c];
#pragma unroll
      for (int i = 0; i < 4; ++i)
#pragma unroll
        for (int jq = 0; jq < 4; ++jq) acc[i][jq] += av[i] * wv[jq];
    }
    __syncthreads();
  }
  __half* vkb = vk + (size_t)b * N_ * H_;
  float4 bav = *(const float4*)(b_attn + k0 + tk * 4);
#pragma unroll
  for (int i = 0; i < 4; ++i) {
    __half2 lo = __floats2half2_rn(acc[i][0] + bav.x, acc[i][1] + bav.y);
    __half2 hi = __floats2half2_rn(acc[i][2] + bav.z, acc[i][3] + bav.w);
    __half2* dst = (__half2*)&vkb[(size_t)(n0 + tn * 4 + i) * H_ + k0 + tk * 4];
    dst[0] = lo;
    dst[1] = hi;
  }
}

// gi_e[t, col, b] = emb[b,t,:]@W_ih[col,:E] + b_ih[col]  (fp16, b fastest)
__global__ __launch_bounds__(256) void k_gie(const float* __restrict__ emb,
                                             const float* __restrict__ W_ih,
                                             const float* __restrict__ b_ih,
                                             __half* __restrict__ gie) {
  int c0 = blockIdx.x * 64;
  int t = blockIdx.y;
  int tid = threadIdx.x;
  int tn = tid >> 4, tk = tid & 15;
  __shared__ float As[64][33];
  __shared__ float Ws[64][33];
  float acc[4][4] = {};
  for (int h0 = 0; h0 < E_; h0 += 32) {
#pragma unroll
    for (int e = 0; e < 8; ++e) {
      int idx = tid + e * 256;
      int r = idx >> 5, c = idx & 31;
      As[r][c] = emb[((size_t)r * L + t) * E_ + h0 + c];
      Ws[r][c] = W_ih[(size_t)(c0 + r) * (E_ + H_) + h0 + c];
    }
    __syncthreads();
#pragma unroll
    for (int c = 0; c < 32; ++c) {
      float av[4], wv[4];
#pragma unroll
      for (int i = 0; i < 4; ++i) av[i] = As[tn * 4 + i][c];
#pragma unroll
      for (int jq = 0; jq < 4; ++jq) wv[jq] = Ws[tk * 4 + jq][c];
#pragma unroll
      for (int i = 0; i < 4; ++i)
#pragma unroll
        for (int jq = 0; jq < 4; ++jq) acc[i][jq] += av[i] * wv[jq];
    }
    __syncthreads();
  }
#pragma unroll
  for (int jq = 0; jq < 4; ++jq) {
    int col = c0 + tk * 4 + jq;
    float bi = b_ih[col];
    __half2 lo = __floats2half2_rn(acc[0][jq] + bi, acc[1][jq] + bi);
    __half2 hi = __floats2half2_rn(acc[2][jq] + bi, acc[3][jq] + bi);
    __half2* dst = (__half2*)(gie + ((size_t)t * G3 + col) * 64 + tn * 4);
    dst[0] = lo;
    dst[1] = hi;
  }
}

// ---------------- the persistent decoder ----------------

__global__ __launch_bounds__(512, 1) void k_step(
    const __half* __restrict__ vk, const __half* __restrict__ val_h,
    const __half* __restrict__ gie, const float* __restrict__ Wq,
    const float* __restrict__ Whh, const float* __restrict__ Wih,
    const float* __restrict__ b_hh, const float* __restrict__ w_cov,
    const float* __restrict__ v_attn, const float* __restrict__ vmask,
    float* __restrict__ cov, float* __restrict__ h32,
    unsigned* __restrict__ h2g, float* __restrict__ out1,
    float* __restrict__ scores, unsigned* __restrict__ ctx2,
    unsigned* __restrict__ scnt, unsigned* __restrict__ bflags,
    unsigned* __restrict__ bgen, float* __restrict__ out_h,
    float* __restrict__ attn_out) {
  const int bx = blockIdx.x;    // 0..255
  const int tid = threadIdx.x;  // 0..511
  const int lane = tid & 63;
  const int wv = __builtin_amdgcn_readfirstlane(tid >> 6);  // 0..7

  __shared__ unsigned sh_h2[16384];      // 64 KB: A: h fp16 [k2][b] | C: ctx
  __shared__ float sh_part[8][2][64];    // A partials
  __shared__ float sh_part6[6][8][64];   // C partials
  __shared__ float sh_qs[512];
  __shared__ float sh_covs[256];
  __shared__ float sh_sc[256];
  __shared__ float sh_at[512];
  __shared__ float sh_red[8], sh_red2[8];
  __shared__ float sh_cpart[4][128][2];

  // ---- hoisted per-lane constants (attention) ----
  const int bq = bx >> 1, hh = bx & 1;  // valid when bx < 128
  float wc8[8], va8[8], mymask = 0.f;
  if (bx < 128) {
    float4 a0 = *(const float4*)(w_cov + lane * 8);
    float4 a1 = *(const float4*)(w_cov + lane * 8 + 4);
    wc8[0] = a0.x; wc8[1] = a0.y; wc8[2] = a0.z; wc8[3] = a0.w;
    wc8[4] = a1.x; wc8[5] = a1.y; wc8[6] = a1.z; wc8[7] = a1.w;
    float4 b0 = *(const float4*)(v_attn + lane * 8);
    float4 b1 = *(const float4*)(v_attn + lane * 8 + 4);
    va8[0] = b0.x; va8[1] = b0.y; va8[2] = b0.z; va8[3] = b0.w;
    va8[4] = b1.x; va8[5] = b1.y; va8[6] = b1.z; va8[7] = b1.w;
    if (tid < 256) mymask = vmask[bq * N_ + hh * 256 + tid];
  }

  for (int t = 0; t < L; ++t) {
    // ================= Phase A: out1[col][b] = [q | gh] =================
#pragma unroll
    for (int e = 0; e < 32; ++e) {
      int idx = tid + e * 512;
      sh_h2[idx] = h2g[idx];
    }
    __syncthreads();
    {
      int pairI = wv & 3, kh = wv >> 2;
      int c0 = __builtin_amdgcn_readfirstlane(bx * 8 + pairI * 2);
      const float* w0p = (c0 < 512) ? (Wq + (size_t)c0 * 512)
                                    : (Whh + (size_t)(c0 - 512) * 512);
      const float* w1p = w0p + 512;
      float a0 = 0.f, a1 = 0.f;
      int base = kh * 128;
#pragma unroll 8
      for (int k2 = 0; k2 < 128; ++k2) {
        float2 hf = uh2f2(sh_h2[(base + k2) * 64 + lane]);
        float2 wa = *(const float2*)(w0p + (base + k2) * 2);
        float2 wb = *(const float2*)(w1p + (base + k2) * 2);
        a0 = fmaf(hf.x, wa.x, a0); a0 = fmaf(hf.y, wa.y, a0);
        a1 = fmaf(hf.x, wb.x, a1); a1 = fmaf(hf.y, wb.y, a1);
      }
      sh_part[pairI * 2 + 0][kh][lane] = a0;
      sh_part[pairI * 2 + 1][kh][lane] = a1;
    }
    __syncthreads();
    {
      int colIdx = tid >> 6;
      int col = bx * 8 + colIdx;
      float acc = sh_part[colIdx][0][lane] + sh_part[colIdx][1][lane];
      if (col >= 512) acc += b_hh[col - 512];
      out1[(size_t)col * 64 + lane] = acc;
    }
    gbar(bflags, bgen, 3 * t + 1);  // ---- sync1: out1 ready ----

    // ================= Phase B: attention (WGs 0..127) =================
    if (bx < 128) {
      sh_qs[tid] = out1[(size_t)tid * 64 + bq];
      if (tid < 256) sh_covs[tid] = cov[bq * N_ + hh * 256 + tid];
      __syncthreads();
      float q8[8];
#pragma unroll
      for (int k = 0; k < 8; ++k) q8[k] = sh_qs[lane * 8 + k];

      const __half2* vkb =
          (const __half2*)vk + ((size_t)bq * N_ + hh * 256) * 256;
      for (int r = 0; r < 32; ++r) {
        int nl = wv * 32 + r;
        float cv = sh_covs[nl];
        float4 raw = *(const float4*)(vkb + (size_t)nl * 256 + lane * 4);
        const __half2* hp = (const __half2*)&raw;
        float p = 0.f;
#pragma unroll
        for (int k = 0; k < 4; ++k) {
          float2 f = __half22float2(hp[k]);
          float e0 = fmaf(cv, wc8[2 * k], q8[2 * k]) + f.x;
          float e1 = fmaf(cv, wc8[2 * k + 1], q8[2 * k + 1]) + f.y;
          p = fmaf(fmaxf(e0, 0.f), va8[2 * k], p);
          p = fmaf(fmaxf(e1, 0.f), va8[2 * k + 1], p);
        }
#pragma unroll
        for (int off = 32; off; off >>= 1) p += __shfl_xor(p, off);
        if (lane == 0) sh_sc[nl] = p;
      }
      __syncthreads();
      if (tid < 256)
        scores[bq * N_ + hh * 256 + tid] = (mymask > 0.f) ? sh_sc[tid] : NEG;
      __syncthreads();
      if (tid == 0) {
        __hip_atomic_fetch_add(&scnt[bq], 1u, __ATOMIC_RELEASE,
                               __HIP_MEMORY_SCOPE_AGENT);
        unsigned target = 2u * (unsigned)(t + 1);
        while (__hip_atomic_load(&scnt[bq], __ATOMIC_ACQUIRE,
                                 __HIP_MEMORY_SCOPE_AGENT) < target) {
          __builtin_amdgcn_s_sleep(1);
        }
      }
      __syncthreads();

      // full softmax (redundant in both pair WGs)
      float sv = scores[bq * N_ + tid];
      float m = sv;
#pragma unroll
      for (int off = 32; off; off >>= 1) m = fmaxf(m, __shfl_xor(m, off));
      if (lane == 0) sh_red[wv] = m;
      __syncthreads();
      m = sh_red[0];
#pragma unroll
      for (int k = 1; k < 8; ++k) m = fmaxf(m, sh_red[k]);
      float p = expf(sv - m);
      float s = p;
#pragma unroll
      for (int off = 32; off; off >>= 1) s += __shfl_xor(s, off);
      if (lane == 0) sh_red2[wv] = s;
      __syncthreads();
      s = 0.f;
#pragma unroll
      for (int k = 0; k < 8; ++k) s += sh_red2[k];
      float a = p * (1.f / s);
      sh_at[tid] = a;
      if ((tid >> 8) == hh) {
        cov[bq * N_ + tid] += a;
        attn_out[((size_t)bq * L + t) * N_ + tid] = a;
      }
      __syncthreads();

      // context for this WG's h-half
      int part = tid >> 7, h2i = tid & 127;
      const __half2* vb =
          (const __half2*)val_h + (size_t)bq * N_ * 256 + hh * 128 + h2i;
      float cx = 0.f, cy = 0.f;
      for (int n = part * 128; n < part * 128 + 128; ++n) {
        float av = sh_at[n];
        float2 f = __half22float2(vb[(size_t)n * 256]);
        cx = fmaf(av, f.x, cx);
        cy = fmaf(av, f.y, cy);
      }
      sh_cpart[part][h2i][0] = cx;
      sh_cpart[part][h2i][1] = cy;
      __syncthreads();
      if (tid < 128) {
        float sx = sh_cpart[0][tid][0] + sh_cpart[1][tid][0] +
                   sh_cpart[2][tid][0] + sh_cpart[3][tid][0];
        float sy = sh_cpart[0][tid][1] + sh_cpart[1][tid][1] +
                   sh_cpart[2][tid][1] + sh_cpart[3][tid][1];
        ctx2[(size_t)(hh * 128 + tid) * 64 + bq] = f2uh2(sx, sy);
      }
    }
    gbar(bflags, bgen, 3 * t + 2);  // ---- sync2: ctx2 ready ----

    // ================= Phase C: gc GEMV + GRU pointwise =================
#pragma unroll
    for (int e = 0; e < 32; ++e) {
      int idx = tid + e * 512;
      sh_h2[idx] = ctx2[idx];
    }
    __syncthreads();
    {
      int jh0 = bx * 2;
      int kb = wv * 32;
      float acc[6] = {0.f, 0.f, 0.f, 0.f, 0.f, 0.f};
      const float* wrow0 = Wih + (size_t)(jh0) * 1024 + 512;
      const float* wrow1 = Wih + (size_t)(jh0 + 1) * 1024 + 512;
      const float* wrow2 = Wih + (size_t)(512 + jh0) * 1024 + 512;
      const float* wrow3 = Wih + (size_t)(512 + jh0 + 1) * 1024 + 512;
      const float* wrow4 = Wih + (size_t)(1024 + jh0) * 1024 + 512;
      const float* wrow5 = Wih + (size_t)(1024 + jh0 + 1) * 1024 + 512;
#pragma unroll 4
      for (int k2 = kb; k2 < kb + 32; ++k2) {
        float2 cf = uh2f2(sh_h2[k2 * 64 + lane]);
        float2 w0 = *(const float2*)(wrow0 + k2 * 2);
        float2 w1 = *(const float2*)(wrow1 + k2 * 2);
        float2 w2 = *(const float2*)(wrow2 + k2 * 2);
        float2 w3 = *(const float2*)(wrow3 + k2 * 2);
        float2 w4 = *(const float2*)(wrow4 + k2 * 2);
        float2 w5 = *(const float2*)(wrow5 + k2 * 2);
        acc[0] = fmaf(cf.x, w0.x, acc[0]); acc[0] = fmaf(cf.y, w0.y, acc[0]);
        acc[1] = fmaf(cf.x, w1.x, acc[1]); acc[1] = fmaf(cf.y, w1.y, acc[1]);
        acc[2] = fmaf(cf.x, w2.x, acc[2]); acc[2] = fmaf(cf.y, w2.y, acc[2]);
        acc[3] = fmaf(cf.x, w3.x, acc[3]); acc[3] = fmaf(cf.y, w3.y, acc[3]);
        acc[4] = fmaf(cf.x, w4.x, acc[4]); acc[4] = fmaf(cf.y, w4.y, acc[4]);
        acc[5] = fmaf(cf.x, w5.x, acc[5]); acc[5] = fmaf(cf.y, w5.y, acc[5]);
      }
#pragma unroll
      for (int c = 0; c < 6; ++c) sh_part6[c][wv][lane] = acc[c];
    }
    __syncthreads();
    if (tid < 128) {
      int sub = tid >> 6, bb = tid & 63;
      int jh = bx * 2 + sub;
      float ac[3];
#pragma unroll
      for (int g = 0; g < 3; ++g) {
        float sgc = 0.f;
#pragma unroll
        for (int w8 = 0; w8 < 8; ++w8) sgc += sh_part6[g * 2 + sub][w8][bb];
        ac[g] = sgc;
      }
      const __half* g = gie + (size_t)t * G3 * 64;
      float gir = __half2float(g[(size_t)jh * 64 + bb]);
      float giz = __half2float(g[(size_t)(512 + jh) * 64 + bb]);
      float gin = __half2float(g[(size_t)(1024 + jh) * 64 + bb]);
      float ghr = out1[(size_t)(512 + jh) * 64 + bb];
      float ghz = out1[(size_t)(1024 + jh) * 64 + bb];
      float ghn = out1[(size_t)(1536 + jh) * 64 + bb];
      float r = 1.f / (1.f + expf(-(gir + ac[0] + ghr)));
      float z = 1.f / (1.f + expf(-(giz + ac[1] + ghz)));
      float nn = tanhf(gin + ac[2] + r * ghn);
      float hp = h32[(size_t)jh * 64 + bb];
      float hv = (1.f - z) * nn + z * hp;
      h32[(size_t)jh * 64 + bb] = hv;
      ((__half*)h2g)[((size_t)bx * 64 + bb) * 2 + sub] = __float2half(hv);
      out_h[((size_t)bb * L + t) * H_ + jh] = hv;
    }
    gbar(bflags, bgen, 3 * t + 3);  // ---- sync3: h ready for next step ----
  }
}

// ---------------- launch ----------------

extern "C" void kernel_launch(void* const* d_in, const int* in_sizes, int n_in,
                              void* d_out, int out_size, void* d_ws, size_t ws_size,
                              hipStream_t stream) {
  const float* emb    = (const float*)d_in[0];
  const float* value  = (const float*)d_in[1];
  const float* vmask  = (const float*)d_in[2];
  const float* state  = (const float*)d_in[3];
  const float* Wq     = (const float*)d_in[4];
  const float* Wk     = (const float*)d_in[5];
  const float* b_attn = (const float*)d_in[6];
  const float* w_cov  = (const float*)d_in[7];
  const float* v_attn = (const float*)d_in[8];
  const float* W_ih   = (const float*)d_in[9];
  const float* W_hh   = (const float*)d_in[10];
  const float* b_ih   = (const float*)d_in[11];
  const float* b_hh   = (const float*)d_in[12];

  float* out = (float*)d_out;
  float* attn_out = out + (size_t)B * L * H_;

  __half* vk_h    = (__half*)d_ws;                         // B*N*H halfs
  __half* val_h   = vk_h + (size_t)B * N_ * H_;            // B*N*H halfs
  __half* gie_h   = val_h + (size_t)B * N_ * H_;           // L*G3*B halfs
  float* h32      = (float*)(gie_h + (size_t)L * G3 * B);  // H*B
  unsigned* h2g   = (unsigned*)(h32 + H_ * B);             // 16384
  float* cov      = (float*)(h2g + 16384);                 // B*N
  float* out1     = cov + (size_t)B * N_;                  // 2048*64
  float* scores   = out1 + (size_t)2048 * 64;              // B*N
  unsigned* ctx2  = (unsigned*)(scores + (size_t)B * N_);  // 16384
  unsigned* scnt  = ctx2 + 16384;                          // 64
  unsigned* bflags = scnt + 64;                            // 256
  unsigned* bgen  = bflags + NWG;                          // 1

  k_init<<<64, 512, 0, stream>>>(state, h32, h2g, cov, scnt, bflags, bgen);
  k_cvt<<<16384, 256, 0, stream>>>(value, val_h);
  k_vk<<<dim3(8, 8, B), 256, 0, stream>>>(value, Wk, b_attn, vk_h);
  k_gie<<<dim3(24, 128), 256, 0, stream>>>(emb, W_ih, b_ih, gie_h);

  void* args[] = {(void*)&vk_h, (void*)&val_h, (void*)&gie_h, (void*)&Wq,
                  (void*)&W_hh, (void*)&W_ih,  (void*)&b_hh,  (void*)&w_cov,
                  (void*)&v_attn, (void*)&vmask, (void*)&cov, (void*)&h32,
                  (void*)&h2g, (void*)&out1, (void*)&scores, (void*)&ctx2,
                  (void*)&scnt, (void*)&bflags, (void*)&bgen, (void*)&out,
                  (void*)&attn_out};
  hipLaunchCooperativeKernel((void*)k_step, dim3(NWG), dim3(512), args, 0,
                             stream);
}

// Round 6
// 10605.195 us; speedup vs baseline: 3.1067x; 3.1067x over previous
//
#include <hip/hip_runtime.h>
#include <hip/hip_fp16.h>
#include <math.h>

#define B 64
#define L 128
#define N_ 512
#define E_ 512
#define H_ 512
#define G3 1536
#define NEG -1e9f

typedef _Float16 h2v __attribute__((ext_vector_type(2)));

__device__ __forceinline__ unsigned f2uh2(float x, float y) {
  __half2 h = __floats2half2_rn(x, y);
  unsigned u;
  __builtin_memcpy(&u, &h, 4);
  return u;
}

// mixed-precision dot2: fp16 pair x fp16 pair + fp32 acc
__device__ __forceinline__ float dot2f(unsigned wu, unsigned hu, float acc) {
  h2v a, b;
  __builtin_memcpy(&a, &wu, 4);
  __builtin_memcpy(&b, &hu, 4);
#if __has_builtin(__builtin_amdgcn_fdot2)
  return __builtin_amdgcn_fdot2(a, b, acc, false);
#else
  return acc + (float)a[0] * (float)b[0] + (float)a[1] * (float)b[1];
#endif
}

// ---------------- precompute kernels (once per call) ----------------

// fp32 -> fp16 copy of value (context path)
__global__ __launch_bounds__(256) void k_cvt(const float* __restrict__ v,
                                             __half* __restrict__ o) {
  size_t i = ((size_t)blockIdx.x * 256 + threadIdx.x) * 4;
  float4 f = *(const float4*)(v + i);
  __half2* d = (__half2*)(o + i);
  d[0] = __floats2half2_rn(f.x, f.y);
  d[1] = __floats2half2_rn(f.z, f.w);
}

// k-major fp16 transposed weights:
// wqhT[k2*2048 + col] = (Wsrc[col][2k2], Wsrc[col][2k2+1]),
//   col<512 -> Wq row col ; col>=512 -> Whh row col-512
// wicT[k2*1536 + col] = (Wih[col][512+2k2], Wih[col][512+2k2+1])
__global__ __launch_bounds__(256) void k_wt(const float* __restrict__ Wq,
                                            const float* __restrict__ Whh,
                                            const float* __restrict__ Wih,
                                            unsigned* __restrict__ wqhT,
                                            unsigned* __restrict__ wicT) {
  int idx = blockIdx.x * 256 + threadIdx.x;  // 0 .. 524287
  {
    int col = idx >> 8, k2 = idx & 255;
    const float* src = (col < 512) ? (Wq + (size_t)col * 512)
                                   : (Whh + (size_t)(col - 512) * 512);
    wqhT[(size_t)k2 * 2048 + col] = f2uh2(src[2 * k2], src[2 * k2 + 1]);
  }
  if (idx < 1536 * 256) {
    int col = idx >> 8, k2 = idx & 255;
    const float* src = Wih + (size_t)col * 1024 + 512;
    wicT[(size_t)k2 * 1536 + col] = f2uh2(src[2 * k2], src[2 * k2 + 1]);
  }
}

// vk[b,n,k] = sum_h value[b,n,h]*Wk[k,h] + b_attn[k]   (fp16)
__global__ __launch_bounds__(256) void k_vk(const float* __restrict__ value,
                                            const float* __restrict__ Wk,
                                            const float* __restrict__ b_attn,
                                            __half* __restrict__ vk) {
  int k0 = blockIdx.x * 64, n0 = blockIdx.y * 64, b = blockIdx.z;
  int tid = threadIdx.x;
  int tn = tid >> 4, tk = tid & 15;
  __shared__ float Vs[64][33];
  __shared__ float Ws[64][33];
  const float* vb = value + (size_t)b * N_ * H_;
  float acc[4][4] = {};
  for (int h0 = 0; h0 < H_; h0 += 32) {
#pragma unroll
    for (int e = 0; e < 8; ++e) {
      int idx = tid + e * 256;
      int r = idx >> 5, c = idx & 31;
      Vs[r][c] = vb[(size_t)(n0 + r) * H_ + h0 + c];
      Ws[r][c] = Wk[(size_t)(k0 + r) * H_ + h0 + c];
    }
    __syncthreads();
#pragma unroll
    for (int c = 0; c < 32; ++c) {
      float av[4], wv[4];
#pragma unroll
      for (int i = 0; i < 4; ++i) av[i] = Vs[tn * 4 + i][c];
#pragma unroll
      for (int jq = 0; jq < 4; ++jq) wv[jq] = Ws[tk * 4 + jq][c];
#pragma unroll
      for (int i = 0; i < 4; ++i)
#pragma unroll
        for (int jq = 0; jq < 4; ++jq) acc[i][jq] += av[i] * wv[jq];
    }
    __syncthreads();
  }
  __half* vkb = vk + (size_t)b * N_ * H_;
  float4 bav = *(const float4*)(b_attn + k0 + tk * 4);
#pragma unroll
  for (int i = 0; i < 4; ++i) {
    __half2 lo = __floats2half2_rn(acc[i][0] + bav.x, acc[i][1] + bav.y);
    __half2 hi = __floats2half2_rn(acc[i][2] + bav.z, acc[i][3] + bav.w);
    __half2* dst = (__half2*)&vkb[(size_t)(n0 + tn * 4 + i) * H_ + k0 + tk * 4];
    dst[0] = lo;
    dst[1] = hi;
  }
}

// gi_e[t, b, col] = emb[b,t,:]@W_ih[col,:E] + b_ih[col]  (fp16, col fastest)
__global__ __launch_bounds__(256) void k_gie(const float* __restrict__ emb,
                                             const float* __restrict__ W_ih,
                                             const float* __restrict__ b_ih,
                                             __half* __restrict__ gie) {
  int c0 = blockIdx.x * 64;
  int t = blockIdx.y;
  int tid = threadIdx.x;
  int tn = tid >> 4, tk = tid & 15;
  __shared__ float As[64][33];
  __shared__ float Ws[64][33];
  float acc[4][4] = {};
  for (int h0 = 0; h0 < E_; h0 += 32) {
#pragma unroll
    for (int e = 0; e < 8; ++e) {
      int idx = tid + e * 256;
      int r = idx >> 5, c = idx & 31;
      As[r][c] = emb[((size_t)r * L + t) * E_ + h0 + c];
      Ws[r][c] = W_ih[(size_t)(c0 + r) * (E_ + H_) + h0 + c];
    }
    __syncthreads();
#pragma unroll
    for (int c = 0; c < 32; ++c) {
      float av[4], wv[4];
#pragma unroll
      for (int i = 0; i < 4; ++i) av[i] = As[tn * 4 + i][c];
#pragma unroll
      for (int jq = 0; jq < 4; ++jq) wv[jq] = Ws[tk * 4 + jq][c];
#pragma unroll
      for (int i = 0; i < 4; ++i)
#pragma unroll
        for (int jq = 0; jq < 4; ++jq) acc[i][jq] += av[i] * wv[jq];
    }
    __syncthreads();
  }
#pragma unroll
  for (int jq = 0; jq < 4; ++jq) {
    int cc = c0 + tk * 4 + jq;
    float bi = b_ih[cc];
#pragma unroll
    for (int i = 0; i < 4; ++i) {
      int bb = tn * 4 + i;
      gie[((size_t)t * B + bb) * G3 + cc] = __float2half(acc[i][jq] + bi);
    }
  }
}

// ---------------- the decoder: one WG per batch, zero grid sync ----------

__global__ __launch_bounds__(1024, 1) void k_dec(
    const __half* __restrict__ vk, const __half* __restrict__ val_h,
    const __half* __restrict__ gie, const unsigned* __restrict__ wqhT,
    const unsigned* __restrict__ wicT, const float* __restrict__ b_hh,
    const float* __restrict__ w_cov, const float* __restrict__ v_attn,
    const float* __restrict__ vmask, const float* __restrict__ state,
    float* __restrict__ out_h, float* __restrict__ attn_out) {
  const int b = blockIdx.x;
  const int tid = threadIdx.x;   // 0..1023
  const int lane = tid & 63;
  const int wv = tid >> 6;       // 0..15

  __shared__ unsigned h2s[256];   // h as fp16 pairs
  __shared__ float h32s[512];     // h fp32 (for z*h term)
  __shared__ float qs[512];
  __shared__ float ghs[1536];
  __shared__ float gcs[1536];
  __shared__ unsigned ctx2s[256]; // ctx as fp16 pairs
  __shared__ float covs[512];
  __shared__ float ats[512];
  __shared__ float scs[512];
  __shared__ float red[16];
  __shared__ float cpart[4][256][2];

  // ---- init LDS state ----
  if (tid < 512) {
    float v = state[b * H_ + tid];
    h32s[tid] = v;
    covs[tid] = 0.f;
  }
  __syncthreads();
  if (tid < 256) h2s[tid] = f2uh2(h32s[2 * tid], h32s[2 * tid + 1]);

  // ---- hoisted per-thread constants ----
  float mymask = (tid < 512) ? vmask[b * N_ + tid] : 0.f;
  float bh0 = 0.f, bh1 = 0.f;
  if (tid >= 256) {
    bh0 = b_hh[2 * tid - 512];
    bh1 = b_hh[2 * tid - 511];
  }
  float wc8[8], va8[8];
  {
    float4 a0 = *(const float4*)(w_cov + lane * 8);
    float4 a1 = *(const float4*)(w_cov + lane * 8 + 4);
    wc8[0] = a0.x; wc8[1] = a0.y; wc8[2] = a0.z; wc8[3] = a0.w;
    wc8[4] = a1.x; wc8[5] = a1.y; wc8[6] = a1.z; wc8[7] = a1.w;
    float4 b0 = *(const float4*)(v_attn + lane * 8);
    float4 b1 = *(const float4*)(v_attn + lane * 8 + 4);
    va8[0] = b0.x; va8[1] = b0.y; va8[2] = b0.z; va8[3] = b0.w;
    va8[4] = b1.x; va8[5] = b1.y; va8[6] = b1.z; va8[7] = b1.w;
  }
  const __half2* vkb = (const __half2*)vk + (size_t)b * N_ * 256;
  const __half2* vvb = (const __half2*)val_h + (size_t)b * N_ * 256;
  __syncthreads();

  for (int t = 0; t < L; ++t) {
    // ===== Phase A: [q | gh] = h @ [Wq;Whh].T  (cols 2tid, 2tid+1) =====
    {
      float a0 = 0.f, a1 = 0.f;
#pragma unroll 8
      for (int k2 = 0; k2 < 256; ++k2) {
        unsigned hv = h2s[k2];
        uint2 w = *(const uint2*)(wqhT + (size_t)k2 * 2048 + 2 * tid);
        a0 = dot2f(w.x, hv, a0);
        a1 = dot2f(w.y, hv, a1);
      }
      int c0 = 2 * tid;
      if (c0 < 512) {
        qs[c0] = a0;
        qs[c0 + 1] = a1;
      } else {
        ghs[c0 - 512] = a0 + bh0;
        ghs[c0 - 511] = a1 + bh1;
      }
    }
    __syncthreads();

    // ===== Phase B: scores (wave wv owns 32 rows) =====
    {
      float q8[8];
#pragma unroll
      for (int k = 0; k < 8; ++k) q8[k] = qs[lane * 8 + k];
      for (int r = 0; r < 32; ++r) {
        int n = wv * 32 + r;
        float cv = covs[n];
        float4 raw = *(const float4*)(vkb + (size_t)n * 256 + lane * 4);
        const __half2* hp = (const __half2*)&raw;
        float p = 0.f;
#pragma unroll
        for (int k = 0; k < 4; ++k) {
          float2 f = __half22float2(hp[k]);
          float e0 = fmaf(cv, wc8[2 * k], q8[2 * k]) + f.x;
          float e1 = fmaf(cv, wc8[2 * k + 1], q8[2 * k + 1]) + f.y;
          p = fmaf(fmaxf(e0, 0.f), va8[2 * k], p);
          p = fmaf(fmaxf(e1, 0.f), va8[2 * k + 1], p);
        }
#pragma unroll
        for (int off = 32; off; off >>= 1) p += __shfl_xor(p, off);
        if (lane == 0) scs[n] = p;
      }
    }
    __syncthreads();

    // ===== softmax over 512 (threads 0..511) =====
    float sv = 0.f, p = 0.f;
    if (tid < 512) {
      sv = (mymask > 0.f) ? scs[tid] : NEG;
      float m = sv;
#pragma unroll
      for (int off = 32; off; off >>= 1) m = fmaxf(m, __shfl_xor(m, off));
      if (lane == 0) red[wv] = m;
    }
    __syncthreads();
    if (tid < 512) {
      float m = red[0];
#pragma unroll
      for (int k = 1; k < 8; ++k) m = fmaxf(m, red[k]);
      p = expf(sv - m);
      float s = p;
#pragma unroll
      for (int off = 32; off; off >>= 1) s += __shfl_xor(s, off);
      if (lane == 0) red[8 + wv] = s;
    }
    __syncthreads();
    if (tid < 512) {
      float s = red[8];
#pragma unroll
      for (int k = 1; k < 8; ++k) s += red[8 + k];
      float a = p * (1.f / s);
      ats[tid] = a;
      covs[tid] += a;
      attn_out[((size_t)b * L + t) * N_ + tid] = a;
    }
    __syncthreads();

    // ===== context: 4 n-quarters x 256 half2 columns =====
    {
      int part = tid >> 8, hc = tid & 255;
      float cx = 0.f, cy = 0.f;
      const __half2* vp = vvb + hc;
      for (int n = part * 128; n < part * 128 + 128; ++n) {
        float a = ats[n];
        float2 f = __half22float2(vp[(size_t)n * 256]);
        cx = fmaf(a, f.x, cx);
        cy = fmaf(a, f.y, cy);
      }
      cpart[part][hc][0] = cx;
      cpart[part][hc][1] = cy;
    }
    __syncthreads();
    if (tid < 256) {
      float sx = cpart[0][tid][0] + cpart[1][tid][0] + cpart[2][tid][0] +
                 cpart[3][tid][0];
      float sy = cpart[0][tid][1] + cpart[1][tid][1] + cpart[2][tid][1] +
                 cpart[3][tid][1];
      ctx2s[tid] = f2uh2(sx, sy);
    }
    __syncthreads();

    // ===== Phase C: gc = ctx @ Wic.T  (threads 0..767, cols 2tid,2tid+1) ===
    if (tid < 768) {
      float a0 = 0.f, a1 = 0.f;
#pragma unroll 8
      for (int k2 = 0; k2 < 256; ++k2) {
        unsigned cv = ctx2s[k2];
        uint2 w = *(const uint2*)(wicT + (size_t)k2 * 1536 + 2 * tid);
        a0 = dot2f(w.x, cv, a0);
        a1 = dot2f(w.y, cv, a1);
      }
      gcs[2 * tid] = a0;
      gcs[2 * tid + 1] = a1;
    }
    __syncthreads();

    // ===== GRU pointwise (threads 0..511) =====
    if (tid < 512) {
      const __half* g = gie + ((size_t)t * B + b) * G3;
      float gir = __half2float(g[tid]);
      float giz = __half2float(g[512 + tid]);
      float gin = __half2float(g[1024 + tid]);
      float r = 1.f / (1.f + expf(-(gir + gcs[tid] + ghs[tid])));
      float z = 1.f / (1.f + expf(-(giz + gcs[512 + tid] + ghs[512 + tid])));
      float nn = tanhf(gin + gcs[1024 + tid] + r * ghs[1024 + tid]);
      float hp = h32s[tid];
      float hv = (1.f - z) * nn + z * hp;
      h32s[tid] = hv;
      out_h[((size_t)b * L + t) * H_ + tid] = hv;
    }
    __syncthreads();
    if (tid < 256) h2s[tid] = f2uh2(h32s[2 * tid], h32s[2 * tid + 1]);
    __syncthreads();
  }
}

// ---------------- launch ----------------

extern "C" void kernel_launch(void* const* d_in, const int* in_sizes, int n_in,
                              void* d_out, int out_size, void* d_ws, size_t ws_size,
                              hipStream_t stream) {
  const float* emb    = (const float*)d_in[0];
  const float* value  = (const float*)d_in[1];
  const float* vmask  = (const float*)d_in[2];
  const float* state  = (const float*)d_in[3];
  const float* Wq     = (const float*)d_in[4];
  const float* Wk     = (const float*)d_in[5];
  const float* b_attn = (const float*)d_in[6];
  const float* w_cov  = (const float*)d_in[7];
  const float* v_attn = (const float*)d_in[8];
  const float* W_ih   = (const float*)d_in[9];
  const float* W_hh   = (const float*)d_in[10];
  const float* b_ih   = (const float*)d_in[11];
  const float* b_hh   = (const float*)d_in[12];

  float* out = (float*)d_out;
  float* attn_out = out + (size_t)B * L * H_;

  __half* vk_h    = (__half*)d_ws;                          // B*N*H halfs
  __half* val_h   = vk_h + (size_t)B * N_ * H_;             // B*N*H halfs
  __half* gie_h   = val_h + (size_t)B * N_ * H_;            // L*B*G3 halfs
  unsigned* wqhT  = (unsigned*)(gie_h + (size_t)L * B * G3);  // 256*2048
  unsigned* wicT  = wqhT + (size_t)256 * 2048;                // 256*1536

  k_cvt<<<16384, 256, 0, stream>>>(value, val_h);
  k_wt<<<2048, 256, 0, stream>>>(Wq, W_hh, W_ih, wqhT, wicT);
  k_vk<<<dim3(8, 8, B), 256, 0, stream>>>(value, Wk, b_attn, vk_h);
  k_gie<<<dim3(24, 128), 256, 0, stream>>>(emb, W_ih, b_ih, gie_h);

  k_dec<<<B, 1024, 0, stream>>>(vk_h, val_h, gie_h, wqhT, wicT, b_hh, w_cov,
                                v_attn, vmask, state, out, attn_out);
}

// Round 8
// 5917.636 us; speedup vs baseline: 5.5676x; 1.7921x over previous
//
#include <hip/hip_runtime.h>
#include <hip/hip_fp16.h>
#include <math.h>

#define B 64
#define L 128
#define N_ 512
#define E_ 512
#define H_ 512
#define G3 1536
#define NEG -1e9f

typedef _Float16 h2v __attribute__((ext_vector_type(2)));

__device__ __forceinline__ unsigned f2uh2(float x, float y) {
  __half2 h = __floats2half2_rn(x, y);
  unsigned u;
  __builtin_memcpy(&u, &h, 4);
  return u;
}

__device__ __forceinline__ float dot2f(unsigned wu, unsigned hu, float acc) {
  h2v a, b;
  __builtin_memcpy(&a, &wu, 4);
  __builtin_memcpy(&b, &hu, 4);
#if __has_builtin(__builtin_amdgcn_fdot2)
  return __builtin_amdgcn_fdot2(a, b, acc, false);
#else
  return acc + (float)a[0] * (float)b[0] + (float)a[1] * (float)b[1];
#endif
}

__device__ __forceinline__ void drain_stores() {
  asm volatile("s_waitcnt vmcnt(0)" ::: "memory");
}

__device__ __forceinline__ unsigned ld_pay(const unsigned* p) {
  return __hip_atomic_load(p, __ATOMIC_RELAXED, __HIP_MEMORY_SCOPE_AGENT);
}
__device__ __forceinline__ void st_pay(unsigned* p, unsigned v) {
  __hip_atomic_store(p, v, __ATOMIC_RELAXED, __HIP_MEMORY_SCOPE_AGENT);
}

// ---------------- precompute kernels (once per call) ----------------

// pay_h init from state; epochs zeroed
__global__ __launch_bounds__(256) void k_init(const float* __restrict__ state,
                                              unsigned* __restrict__ pay_h,
                                              unsigned* __restrict__ ep) {
  int i = blockIdx.x * 256 + threadIdx.x;  // 0..16383
  {
    int b = i >> 8, j2 = i & 255;
    pay_h[i] = f2uh2(state[b * H_ + 2 * j2], state[b * H_ + 2 * j2 + 1]);
  }
  if (i < 256 * 16) ep[i] = 0u;
}

// value[b][n][h] f32 -> valT[b][h][n] fp16
__global__ __launch_bounds__(256) void k_cvtT(const float* __restrict__ v,
                                              __half* __restrict__ o) {
  int h0 = blockIdx.x * 32, n0 = blockIdx.y * 32, b = blockIdx.z;
  int tid = threadIdx.x;
  __shared__ float ts[32][33];
#pragma unroll
  for (int e = 0; e < 4; ++e) {
    int idx = tid + e * 256;
    int r = idx >> 5, c = idx & 31;
    ts[r][c] = v[((size_t)b * N_ + n0 + r) * H_ + h0 + c];
  }
  __syncthreads();
#pragma unroll
  for (int e = 0; e < 4; ++e) {
    int idx = tid + e * 256;
    int hr = idx >> 5, nc = idx & 31;
    o[((size_t)b * H_ + h0 + hr) * N_ + n0 + nc] = __float2half(ts[nc][hr]);
  }
}

// wqhT[k2*2048+col] = fp16 pair of [Wq;Whh] row `col`, elems 2k2,2k2+1
// wicT3[k2*1536 + 3j+gate] = fp16 pair of Wih[gate*512+j][512+2k2 ..]
__global__ __launch_bounds__(256) void k_wt(const float* __restrict__ Wq,
                                            const float* __restrict__ Whh,
                                            const float* __restrict__ Wih,
                                            unsigned* __restrict__ wqhT,
                                            unsigned* __restrict__ wicT3) {
  int idx = blockIdx.x * 256 + threadIdx.x;  // 0..524287
  {
    int col = idx >> 8, k2 = idx & 255;
    const float* src = (col < 512) ? (Wq + (size_t)col * 512)
                                   : (Whh + (size_t)(col - 512) * 512);
    wqhT[(size_t)k2 * 2048 + col] = f2uh2(src[2 * k2], src[2 * k2 + 1]);
  }
  if (idx < 1536 * 256) {
    int colp = idx >> 8, k2 = idx & 255;
    int j = colp / 3, gate = colp - 3 * j;
    const float* src = Wih + (size_t)(gate * 512 + j) * 1024 + 512;
    wicT3[(size_t)k2 * 1536 + colp] = f2uh2(src[2 * k2], src[2 * k2 + 1]);
  }
}

// vk[b,n,k] = sum_h value[b,n,h]*Wk[k,h] + b_attn[k]   (fp16)
__global__ __launch_bounds__(256) void k_vk(const float* __restrict__ value,
                                            const float* __restrict__ Wk,
                                            const float* __restrict__ b_attn,
                                            __half* __restrict__ vk) {
  int k0 = blockIdx.x * 64, n0 = blockIdx.y * 64, b = blockIdx.z;
  int tid = threadIdx.x;
  int tn = tid >> 4, tk = tid & 15;
  __shared__ float Vs[64][33];
  __shared__ float Ws[64][33];
  const float* vb = value + (size_t)b * N_ * H_;
  float acc[4][4] = {};
  for (int h0 = 0; h0 < H_; h0 += 32) {
#pragma unroll
    for (int e = 0; e < 8; ++e) {
      int idx = tid + e * 256;
      int r = idx >> 5, c = idx & 31;
      Vs[r][c] = vb[(size_t)(n0 + r) * H_ + h0 + c];
      Ws[r][c] = Wk[(size_t)(k0 + r) * H_ + h0 + c];
    }
    __syncthreads();
#pragma unroll
    for (int c = 0; c < 32; ++c) {
      float av[4], wv[4];
#pragma unroll
      for (int i = 0; i < 4; ++i) av[i] = Vs[tn * 4 + i][c];
#pragma unroll
      for (int jq = 0; jq < 4; ++jq) wv[jq] = Ws[tk * 4 + jq][c];
#pragma unroll
      for (int i = 0; i < 4; ++i)
#pragma unroll
        for (int jq = 0; jq < 4; ++jq) acc[i][jq] += av[i] * wv[jq];
    }
    __syncthreads();
  }
  __half* vkb = vk + (size_t)b * N_ * H_;
  float4 bav = *(const float4*)(b_attn + k0 + tk * 4);
#pragma unroll
  for (int i = 0; i < 4; ++i) {
    __half2 lo = __floats2half2_rn(acc[i][0] + bav.x, acc[i][1] + bav.y);
    __half2 hi = __floats2half2_rn(acc[i][2] + bav.z, acc[i][3] + bav.w);
    __half2* dst = (__half2*)&vkb[(size_t)(n0 + tn * 4 + i) * H_ + k0 + tk * 4];
    dst[0] = lo;
    dst[1] = hi;
  }
}

// gi_e[t, b, col] = emb[b,t,:]@W_ih[col,:E] + b_ih[col]  (fp16, col fastest)
__global__ __launch_bounds__(256) void k_gie(const float* __restrict__ emb,
                                             const float* __restrict__ W_ih,
                                             const float* __restrict__ b_ih,
                                             __half* __restrict__ gie) {
  int c0 = blockIdx.x * 64;
  int t = blockIdx.y;
  int tid = threadIdx.x;
  int tn = tid >> 4, tk = tid & 15;
  __shared__ float As[64][33];
  __shared__ float Ws[64][33];
  float acc[4][4] = {};
  for (int h0 = 0; h0 < E_; h0 += 32) {
#pragma unroll
    for (int e = 0; e < 8; ++e) {
      int idx = tid + e * 256;
      int r = idx >> 5, c = idx & 31;
      As[r][c] = emb[((size_t)r * L + t) * E_ + h0 + c];
      Ws[r][c] = W_ih[(size_t)(c0 + r) * (E_ + H_) + h0 + c];
    }
    __syncthreads();
#pragma unroll
    for (int c = 0; c < 32; ++c) {
      float av[4], wv[4];
#pragma unroll
      for (int i = 0; i < 4; ++i) av[i] = As[tn * 4 + i][c];
#pragma unroll
      for (int jq = 0; jq < 4; ++jq) wv[jq] = Ws[tk * 4 + jq][c];
#pragma unroll
      for (int i = 0; i < 4; ++i)
#pragma unroll
        for (int jq = 0; jq < 4; ++jq) acc[i][jq] += av[i] * wv[jq];
    }
    __syncthreads();
  }
#pragma unroll
  for (int jq = 0; jq < 4; ++jq) {
    int cc = c0 + tk * 4 + jq;
    float bi = b_ih[cc];
#pragma unroll
    for (int i = 0; i < 4; ++i) {
      int bb = tn * 4 + i;
      gie[((size_t)t * B + bb) * G3 + cc] = __float2half(acc[i][jq] + bi);
    }
  }
}

// ---------------- decoder: 4 WGs per batch, point-to-point flag sync -------

__global__ __launch_bounds__(512, 1) void k_dec(
    const __half* __restrict__ vk, const __half* __restrict__ valT,
    const __half* __restrict__ gie, const unsigned* __restrict__ wqhT,
    const unsigned* __restrict__ wicT3, const float* __restrict__ b_hh,
    const float* __restrict__ w_cov, const float* __restrict__ v_attn,
    const float* __restrict__ vmask, const float* __restrict__ state,
    unsigned* __restrict__ pay_q, unsigned* __restrict__ pay_gh,
    unsigned* __restrict__ pay_sc, unsigned* __restrict__ pay_ctx,
    unsigned* __restrict__ pay_h, unsigned* __restrict__ ep,
    float* __restrict__ out_h, float* __restrict__ attn_out) {
  const int wg = blockIdx.x;   // 0..255
  const int b = wg >> 2;
  const int g = wg & 3;
  const int tid = threadIdx.x; // 0..511
  const int lane = tid & 63;
  const int wvi = tid >> 6;    // 0..7

  __shared__ unsigned sh_h2[256];
  __shared__ float sh_pA[2][256][2];
  __shared__ float sh_q[512];
  __shared__ float sh_cov[128];
  __shared__ float sh_scl[128];
  __shared__ float sh_sc[512];
  __shared__ float sh_at[512];
  __shared__ float sh_red[16];
  __shared__ float sh_cp[4][128];
  __shared__ unsigned sh_ctx2[256];
  __shared__ float sh_gc[384];
  __shared__ float sh_hv[128];
  __shared__ float sh_h32[128];

  // ---- hoisted constants / local state ----
  if (tid < 128) {
    sh_h32[tid] = state[b * H_ + 128 * g + tid];
    sh_cov[tid] = 0.f;
  }
  float mymask = (tid < 128) ? vmask[b * N_ + 128 * g + tid] : 0.f;
  float bh0 = 0.f, bh1 = 0.f;
  if (g >= 1 && tid < 256) {
    bh0 = b_hh[(g - 1) * 512 + 2 * tid];
    bh1 = b_hh[(g - 1) * 512 + 2 * tid + 1];
  }
  float wc8[8], va8[8];
  {
    float4 a0 = *(const float4*)(w_cov + lane * 8);
    float4 a1 = *(const float4*)(w_cov + lane * 8 + 4);
    wc8[0] = a0.x; wc8[1] = a0.y; wc8[2] = a0.z; wc8[3] = a0.w;
    wc8[4] = a1.x; wc8[5] = a1.y; wc8[6] = a1.z; wc8[7] = a1.w;
    float4 b0 = *(const float4*)(v_attn + lane * 8);
    float4 b1 = *(const float4*)(v_attn + lane * 8 + 4);
    va8[0] = b0.x; va8[1] = b0.y; va8[2] = b0.z; va8[3] = b0.w;
    va8[4] = b1.x; va8[5] = b1.y; va8[6] = b1.z; va8[7] = b1.w;
  }
  const __half* vkb = vk + ((size_t)b * N_ + 128 * g) * H_;
  unsigned* myep = ep + wg * 16;
  __syncthreads();

  for (int t = 0; t < L; ++t) {
    // ---- wait all quad members' h (prev C); load full h ----
    if (tid < 4) {
      const unsigned* f = ep + (b * 4 + tid) * 16;
      unsigned tgt = 4u * (unsigned)t;
      while (__hip_atomic_load(f, __ATOMIC_RELAXED,
                               __HIP_MEMORY_SCOPE_AGENT) < tgt)
        __builtin_amdgcn_s_sleep(1);
    }
    __syncthreads();
    if (tid < 256) sh_h2[tid] = ld_pay(&pay_h[b * 256 + tid]);
    __syncthreads();

    // ===== Phase A: cols [512g .. 512g+512) of [q|gh], k-split x2 =====
    {
      int kh = tid >> 8, ci = tid & 255;
      const unsigned* wp = wqhT + 512 * g + 2 * ci;
      float a0 = 0.f, a1 = 0.f;
      int k2b = kh * 128;
#pragma unroll 8
      for (int k2i = 0; k2i < 128; ++k2i) {
        int k2 = k2b + k2i;
        unsigned hv = sh_h2[k2];
        uint2 w = *(const uint2*)(wp + (size_t)k2 * 2048);
        a0 = dot2f(w.x, hv, a0);
        a1 = dot2f(w.y, hv, a1);
      }
      sh_pA[kh][ci][0] = a0;
      sh_pA[kh][ci][1] = a1;
    }
    __syncthreads();
    if (tid < 256) {
      float a0 = sh_pA[0][tid][0] + sh_pA[1][tid][0];
      float a1 = sh_pA[0][tid][1] + sh_pA[1][tid][1];
      if (g == 0) {
        st_pay(&pay_q[b * 512 + 2 * tid], __float_as_uint(a0));
        st_pay(&pay_q[b * 512 + 2 * tid + 1], __float_as_uint(a1));
      } else {
        int idx = (g - 1) * 512 + 2 * tid;
        st_pay(&pay_gh[b * 1536 + idx], __float_as_uint(a0 + bh0));
        st_pay(&pay_gh[b * 1536 + idx + 1], __float_as_uint(a1 + bh1));
      }
    }
    drain_stores();
    __syncthreads();
    if (tid == 0)
      __hip_atomic_store(myep, 4u * t + 1u, __ATOMIC_RELAXED,
                         __HIP_MEMORY_SCOPE_AGENT);

    // ---- wait q (member 0) ----
    if (tid == 0) {
      const unsigned* f = ep + (b * 4) * 16;
      unsigned tgt = 4u * (unsigned)t + 1u;
      while (__hip_atomic_load(f, __ATOMIC_RELAXED,
                               __HIP_MEMORY_SCOPE_AGENT) < tgt)
        __builtin_amdgcn_s_sleep(1);
    }
    __syncthreads();
    sh_q[tid] = __uint_as_float(ld_pay(&pay_q[b * 512 + tid]));
    __syncthreads();

    // ===== Phase B: scores for rows [128g..128g+128) =====
    {
      float q8[8];
#pragma unroll
      for (int k = 0; k < 8; ++k) q8[k] = sh_q[lane * 8 + k];
      for (int r = 0; r < 16; ++r) {
        int nl = wvi * 16 + r;
        float cv = sh_cov[nl];
        float4 raw = *(const float4*)(vkb + (size_t)nl * H_ + lane * 8);
        const __half2* hp = (const __half2*)&raw;
        float p = 0.f;
#pragma unroll
        for (int k = 0; k < 4; ++k) {
          float2 f = __half22float2(hp[k]);
          float e0 = fmaf(cv, wc8[2 * k], q8[2 * k]) + f.x;
          float e1 = fmaf(cv, wc8[2 * k + 1], q8[2 * k + 1]) + f.y;
          p = fmaf(fmaxf(e0, 0.f), va8[2 * k], p);
          p = fmaf(fmaxf(e1, 0.f), va8[2 * k + 1], p);
        }
#pragma unroll
        for (int off = 32; off; off >>= 1) p += __shfl_xor(p, off);
        if (lane == 0) sh_scl[nl] = p;
      }
    }
    __syncthreads();
    if (tid < 128)
      st_pay(&pay_sc[b * 512 + 128 * g + tid],
             __float_as_uint(mymask > 0.f ? sh_scl[tid] : NEG));
    drain_stores();
    __syncthreads();
    if (tid == 0)
      __hip_atomic_store(myep, 4u * t + 2u, __ATOMIC_RELAXED,
                         __HIP_MEMORY_SCOPE_AGENT);
    if (tid < 4) {
      const unsigned* f = ep + (b * 4 + tid) * 16;
      unsigned tgt = 4u * (unsigned)t + 2u;
      while (__hip_atomic_load(f, __ATOMIC_RELAXED,
                               __HIP_MEMORY_SCOPE_AGENT) < tgt)
        __builtin_amdgcn_s_sleep(1);
    }
    __syncthreads();
    sh_sc[tid] = __uint_as_float(ld_pay(&pay_sc[b * 512 + tid]));
    __syncthreads();

    // ===== softmax over 512 (redundant in all 4 WGs) =====
    {
      float sv = sh_sc[tid];
      float m = sv;
#pragma unroll
      for (int off = 32; off; off >>= 1) m = fmaxf(m, __shfl_xor(m, off));
      if (lane == 0) sh_red[wvi] = m;
      __syncthreads();
      m = sh_red[0];
#pragma unroll
      for (int k = 1; k < 8; ++k) m = fmaxf(m, sh_red[k]);
      float p = expf(sv - m);
      float s = p;
#pragma unroll
      for (int off = 32; off; off >>= 1) s += __shfl_xor(s, off);
      if (lane == 0) sh_red[8 + wvi] = s;
      __syncthreads();
      s = sh_red[8];
#pragma unroll
      for (int k = 1; k < 8; ++k) s += sh_red[8 + k];
      sh_at[tid] = p * (1.f / s);
    }
    __syncthreads();
    if (tid < 128) {
      float a = sh_at[128 * g + tid];
      sh_cov[tid] += a;
      attn_out[((size_t)b * L + t) * N_ + 128 * g + tid] = a;
    }

    // ===== context slice: h-cols [128g..128g+128), 4 n-parts =====
    {
      int col = 128 * g + (tid & 127);
      int part = tid >> 7;
      const __half* vp = valT + ((size_t)b * H_ + col) * N_ + part * 128;
      float acc = 0.f;
#pragma unroll
      for (int i = 0; i < 16; ++i) {
        uint4 u = *(const uint4*)(vp + i * 8);
        const __half2* hp = (const __half2*)&u;
#pragma unroll
        for (int k = 0; k < 4; ++k) {
          float2 f = __half22float2(hp[k]);
          acc = fmaf(sh_at[part * 128 + i * 8 + 2 * k], f.x, acc);
          acc = fmaf(sh_at[part * 128 + i * 8 + 2 * k + 1], f.y, acc);
        }
      }
      sh_cp[part][tid & 127] = acc;
    }
    __syncthreads();
    if (tid < 128) {
      float cx = sh_cp[0][tid] + sh_cp[1][tid] + sh_cp[2][tid] + sh_cp[3][tid];
      st_pay(&pay_ctx[b * 512 + 128 * g + tid], __float_as_uint(cx));
    }
    drain_stores();
    __syncthreads();
    if (tid == 0)
      __hip_atomic_store(myep, 4u * t + 3u, __ATOMIC_RELAXED,
                         __HIP_MEMORY_SCOPE_AGENT);
    if (tid < 4) {
      const unsigned* f = ep + (b * 4 + tid) * 16;
      unsigned tgt = 4u * (unsigned)t + 3u;
      while (__hip_atomic_load(f, __ATOMIC_RELAXED,
                               __HIP_MEMORY_SCOPE_AGENT) < tgt)
        __builtin_amdgcn_s_sleep(1);
    }
    __syncthreads();
    if (tid < 256) {
      float c0 = __uint_as_float(ld_pay(&pay_ctx[b * 512 + 2 * tid]));
      float c1 = __uint_as_float(ld_pay(&pay_ctx[b * 512 + 2 * tid + 1]));
      sh_ctx2[tid] = f2uh2(c0, c1);
    }
    __syncthreads();

    // ===== Phase C: gc for j in [128g..128g+128), gate-interleaved =====
    if (tid < 384) {
      const unsigned* wp = wicT3 + 384 * g + tid;
      float acc = 0.f;
#pragma unroll 8
      for (int k2 = 0; k2 < 256; ++k2)
        acc = dot2f(wp[(size_t)k2 * 1536], sh_ctx2[k2], acc);
      sh_gc[tid] = acc;
    }
    __syncthreads();

    // ===== GRU pointwise for j in [128g..128g+128) =====
    if (tid < 128) {
      int j = 128 * g + tid;
      const __half* gp = gie + ((size_t)t * B + b) * G3;
      float gir = __half2float(gp[j]);
      float giz = __half2float(gp[512 + j]);
      float gin = __half2float(gp[1024 + j]);
      float ghr = __uint_as_float(ld_pay(&pay_gh[b * 1536 + j]));
      float ghz = __uint_as_float(ld_pay(&pay_gh[b * 1536 + 512 + j]));
      float ghn = __uint_as_float(ld_pay(&pay_gh[b * 1536 + 1024 + j]));
      float r = 1.f / (1.f + expf(-(gir + sh_gc[3 * tid] + ghr)));
      float z = 1.f / (1.f + expf(-(giz + sh_gc[3 * tid + 1] + ghz)));
      float nn = tanhf(gin + sh_gc[3 * tid + 2] + r * ghn);
      float hp = sh_h32[tid];
      float hv = (1.f - z) * nn + z * hp;
      sh_h32[tid] = hv;
      sh_hv[tid] = hv;
      out_h[((size_t)b * L + t) * H_ + j] = hv;
    }
    __syncthreads();
    if (tid < 64)
      st_pay(&pay_h[b * 256 + 64 * g + tid],
             f2uh2(sh_hv[2 * tid], sh_hv[2 * tid + 1]));
    drain_stores();
    __syncthreads();
    if (tid == 0)
      __hip_atomic_store(myep, 4u * t + 4u, __ATOMIC_RELAXED,
                         __HIP_MEMORY_SCOPE_AGENT);
  }
}

// ---------------- launch ----------------

extern "C" void kernel_launch(void* const* d_in, const int* in_sizes, int n_in,
                              void* d_out, int out_size, void* d_ws, size_t ws_size,
                              hipStream_t stream) {
  const float* emb    = (const float*)d_in[0];
  const float* value  = (const float*)d_in[1];
  const float* vmask  = (const float*)d_in[2];
  const float* state  = (const float*)d_in[3];
  const float* Wq     = (const float*)d_in[4];
  const float* Wk     = (const float*)d_in[5];
  const float* b_attn = (const float*)d_in[6];
  const float* w_cov  = (const float*)d_in[7];
  const float* v_attn = (const float*)d_in[8];
  const float* W_ih   = (const float*)d_in[9];
  const float* W_hh   = (const float*)d_in[10];
  const float* b_ih   = (const float*)d_in[11];
  const float* b_hh   = (const float*)d_in[12];

  float* out = (float*)d_out;
  float* attn_out = out + (size_t)B * L * H_;

  __half* vk_h     = (__half*)d_ws;                          // B*N*H
  __half* valT     = vk_h + (size_t)B * N_ * H_;             // B*H*N
  __half* gie_h    = valT + (size_t)B * N_ * H_;             // L*B*G3
  unsigned* wqhT   = (unsigned*)(gie_h + (size_t)L * B * G3);  // 256*2048
  unsigned* wicT3  = wqhT + (size_t)256 * 2048;                // 256*1536
  unsigned* pay_q  = wicT3 + (size_t)256 * 1536;               // B*512
  unsigned* pay_gh = pay_q + B * 512;                          // B*1536
  unsigned* pay_sc = pay_gh + B * 1536;                        // B*512
  unsigned* pay_ctx= pay_sc + B * 512;                         // B*512
  unsigned* pay_h  = pay_ctx + B * 512;                        // B*256
  unsigned* ep     = pay_h + B * 256;                          // 256*16

  k_init<<<64, 256, 0, stream>>>(state, pay_h, ep);
  k_cvtT<<<dim3(16, 16, B), 256, 0, stream>>>(value, valT);
  k_wt<<<2048, 256, 0, stream>>>(Wq, W_hh, W_ih, wqhT, wicT3);
  k_vk<<<dim3(8, 8, B), 256, 0, stream>>>(value, Wk, b_attn, vk_h);
  k_gie<<<dim3(24, 128), 256, 0, stream>>>(emb, W_ih, b_ih, gie_h);

  k_dec<<<256, 512, 0, stream>>>(vk_h, valT, gie_h, wqhT, wicT3, b_hh, w_cov,
                                 v_attn, vmask, state, pay_q, pay_gh, pay_sc,
                                 pay_ctx, pay_h, ep, out, attn_out);
}

// Round 9
// 5289.689 us; speedup vs baseline: 6.2285x; 1.1187x over previous
//
#include <hip/hip_runtime.h>
#include <hip/hip_fp16.h>
#include <math.h>

#define B 64
#define L 128
#define N_ 512
#define E_ 512
#define H_ 512
#define G3 1536
#define NEG -1e9f
#define SMEM_BYTES 149056

typedef _Float16 h2v __attribute__((ext_vector_type(2)));

__device__ __forceinline__ unsigned f2uh2(float x, float y) {
  __half2 h = __floats2half2_rn(x, y);
  unsigned u;
  __builtin_memcpy(&u, &h, 4);
  return u;
}

__device__ __forceinline__ float dot2f(unsigned wu, unsigned hu, float acc) {
  h2v a, b;
  __builtin_memcpy(&a, &wu, 4);
  __builtin_memcpy(&b, &hu, 4);
#if __has_builtin(__builtin_amdgcn_fdot2)
  return __builtin_amdgcn_fdot2(a, b, acc, false);
#else
  return acc + (float)a[0] * (float)b[0] + (float)a[1] * (float)b[1];
#endif
}

__device__ __forceinline__ void drain_stores() {
  asm volatile("s_waitcnt vmcnt(0)" ::: "memory");
}

__device__ __forceinline__ unsigned ld_pay(const unsigned* p) {
  return __hip_atomic_load(p, __ATOMIC_RELAXED, __HIP_MEMORY_SCOPE_AGENT);
}
__device__ __forceinline__ void st_pay(unsigned* p, unsigned v) {
  __hip_atomic_store(p, v, __ATOMIC_RELAXED, __HIP_MEMORY_SCOPE_AGENT);
}
__device__ __forceinline__ void wait_flag(const unsigned* p, unsigned tgt) {
  while (__hip_atomic_load(p, __ATOMIC_RELAXED, __HIP_MEMORY_SCOPE_AGENT) < tgt)
    __builtin_amdgcn_s_sleep(1);
}

// ---------------- precompute kernels (once per call) ----------------

__global__ __launch_bounds__(256) void k_init(const float* __restrict__ state,
                                              unsigned* __restrict__ pay_h,
                                              unsigned* __restrict__ ep) {
  int i = blockIdx.x * 256 + threadIdx.x;  // 0..16383
  {
    int b = i >> 8, k2 = i & 255;
    pay_h[i] = f2uh2(state[b * H_ + 2 * k2], state[b * H_ + 2 * k2 + 1]);
  }
  if (i < 256) ep[i] = 0u;
}

// value[b][n][h] f32 -> valT[b][h][n] fp16
__global__ __launch_bounds__(256) void k_cvtT(const float* __restrict__ v,
                                              __half* __restrict__ o) {
  int h0 = blockIdx.x * 32, n0 = blockIdx.y * 32, b = blockIdx.z;
  int tid = threadIdx.x;
  __shared__ float ts[32][33];
#pragma unroll
  for (int e = 0; e < 4; ++e) {
    int idx = tid + e * 256;
    int r = idx >> 5, c = idx & 31;
    ts[r][c] = v[((size_t)b * N_ + n0 + r) * H_ + h0 + c];
  }
  __syncthreads();
#pragma unroll
  for (int e = 0; e < 4; ++e) {
    int idx = tid + e * 256;
    int hr = idx >> 5, nc = idx & 31;
    o[((size_t)b * H_ + h0 + hr) * N_ + n0 + nc] = __float2half(ts[nc][hr]);
  }
}

// wqhA[m][k2p][c] uint2: member-m A-slice, col=64m+c, elems 4k2p..4k2p+3
// wicC[m][k2p][cc] uint2: C-slice gate-interleaved, cc=3*ii+gate, j=16m+ii
__global__ __launch_bounds__(256) void k_wt(const float* __restrict__ Wq,
                                            const float* __restrict__ Whh,
                                            const float* __restrict__ Wih,
                                            uint2* __restrict__ wqhA,
                                            uint2* __restrict__ wicC) {
  int idx = blockIdx.x * 256 + threadIdx.x;  // 0..262143
  {
    int m = idx >> 13, rem = idx & 8191;
    int k2p = rem >> 6, c = rem & 63;
    int col = 64 * m + c;
    const float* s = (col < 512) ? (Wq + (size_t)col * 512)
                                 : (Whh + (size_t)(col - 512) * 512);
    wqhA[idx] = make_uint2(f2uh2(s[4 * k2p], s[4 * k2p + 1]),
                           f2uh2(s[4 * k2p + 2], s[4 * k2p + 3]));
  }
  if (idx < 32 * 128 * 48) {
    int m = idx / 6144, rem = idx % 6144;
    int k2p = rem / 48, cc = rem % 48;
    int ii = cc / 3, gate = cc % 3;
    int j = 16 * m + ii;
    const float* s = Wih + (size_t)(gate * 512 + j) * 1024 + 512;
    wicC[idx] = make_uint2(f2uh2(s[4 * k2p], s[4 * k2p + 1]),
                           f2uh2(s[4 * k2p + 2], s[4 * k2p + 3]));
  }
}

// vk[b,n,k] = sum_h value[b,n,h]*Wk[k,h] + b_attn[k]   (fp16)
__global__ __launch_bounds__(256) void k_vk(const float* __restrict__ value,
                                            const float* __restrict__ Wk,
                                            const float* __restrict__ b_attn,
                                            __half* __restrict__ vk) {
  int k0 = blockIdx.x * 64, n0 = blockIdx.y * 64, b = blockIdx.z;
  int tid = threadIdx.x;
  int tn = tid >> 4, tk = tid & 15;
  __shared__ float Vs[64][33];
  __shared__ float Ws[64][33];
  const float* vb = value + (size_t)b * N_ * H_;
  float acc[4][4] = {};
  for (int h0 = 0; h0 < H_; h0 += 32) {
#pragma unroll
    for (int e = 0; e < 8; ++e) {
      int idx = tid + e * 256;
      int r = idx >> 5, c = idx & 31;
      Vs[r][c] = vb[(size_t)(n0 + r) * H_ + h0 + c];
      Ws[r][c] = Wk[(size_t)(k0 + r) * H_ + h0 + c];
    }
    __syncthreads();
#pragma unroll
    for (int c = 0; c < 32; ++c) {
      float av[4], wv[4];
#pragma unroll
      for (int i = 0; i < 4; ++i) av[i] = Vs[tn * 4 + i][c];
#pragma unroll
      for (int jq = 0; jq < 4; ++jq) wv[jq] = Ws[tk * 4 + jq][c];
#pragma unroll
      for (int i = 0; i < 4; ++i)
#pragma unroll
        for (int jq = 0; jq < 4; ++jq) acc[i][jq] += av[i] * wv[jq];
    }
    __syncthreads();
  }
  __half* vkb = vk + (size_t)b * N_ * H_;
  float4 bav = *(const float4*)(b_attn + k0 + tk * 4);
#pragma unroll
  for (int i = 0; i < 4; ++i) {
    __half2 lo = __floats2half2_rn(acc[i][0] + bav.x, acc[i][1] + bav.y);
    __half2 hi = __floats2half2_rn(acc[i][2] + bav.z, acc[i][3] + bav.w);
    __half2* dst = (__half2*)&vkb[(size_t)(n0 + tn * 4 + i) * H_ + k0 + tk * 4];
    dst[0] = lo;
    dst[1] = hi;
  }
}

// gi_e triple-interleaved: gie3[t][b][3j+gate] = emb[b,t,:]@W_ih[gate*512+j,:E]+b_ih
__global__ __launch_bounds__(256) void k_gie(const float* __restrict__ emb,
                                             const float* __restrict__ W_ih,
                                             const float* __restrict__ b_ih,
                                             __half* __restrict__ gie3) {
  int c0 = blockIdx.x * 64;
  int t = blockIdx.y;
  int tid = threadIdx.x;
  int tn = tid >> 4, tk = tid & 15;
  __shared__ float As[64][33];
  __shared__ float Ws[64][33];
  float acc[4][4] = {};
  for (int h0 = 0; h0 < E_; h0 += 32) {
#pragma unroll
    for (int e = 0; e < 8; ++e) {
      int idx = tid + e * 256;
      int r = idx >> 5, c = idx & 31;
      As[r][c] = emb[((size_t)r * L + t) * E_ + h0 + c];
      Ws[r][c] = W_ih[(size_t)(c0 + r) * (E_ + H_) + h0 + c];
    }
    __syncthreads();
#pragma unroll
    for (int c = 0; c < 32; ++c) {
      float av[4], wv[4];
#pragma unroll
      for (int i = 0; i < 4; ++i) av[i] = As[tn * 4 + i][c];
#pragma unroll
      for (int jq = 0; jq < 4; ++jq) wv[jq] = Ws[tk * 4 + jq][c];
#pragma unroll
      for (int i = 0; i < 4; ++i)
#pragma unroll
        for (int jq = 0; jq < 4; ++jq) acc[i][jq] += av[i] * wv[jq];
    }
    __syncthreads();
  }
#pragma unroll
  for (int jq = 0; jq < 4; ++jq) {
    int scol = c0 + tk * 4 + jq;
    int dcol = 3 * (scol & 511) + (scol >> 9);
    float bi = b_ih[scol];
#pragma unroll
    for (int i = 0; i < 4; ++i) {
      int bb = tn * 4 + i;
      gie3[((size_t)t * B + bb) * G3 + dcol] = __float2half(acc[i][jq] + bi);
    }
  }
}

// ---------------- decoder: 8 XCD-local groups of 32 WGs, LDS weights ------

__global__ __launch_bounds__(512, 1) void k_dec(
    const __half* __restrict__ vk, const __half* __restrict__ valT,
    const __half* __restrict__ gie3, const uint2* __restrict__ wqhA,
    const uint2* __restrict__ wicC, const float* __restrict__ b_hh,
    const float* __restrict__ w_cov, const float* __restrict__ v_attn,
    const float* __restrict__ vmask, const float* __restrict__ state,
    unsigned* __restrict__ pay_q, unsigned* __restrict__ pay_gh3,
    unsigned* __restrict__ pay_sc, unsigned* __restrict__ pay_ctx,
    unsigned* __restrict__ pay_h, unsigned* __restrict__ ep,
    float* __restrict__ out_h, float* __restrict__ attn_out) {
  extern __shared__ char smem[];
  uint2* wa       = (uint2*)smem;                   // [128 k2p][64 c]
  uint2* wc       = (uint2*)(smem + 65536);         // [128 k2p][48 cc]
  unsigned* hA    = (unsigned*)(smem + 114688);     // [128][8][2]
  unsigned* hC    = (unsigned*)(smem + 122880);     // [128][8][2]
  float* pA       = (float*)(smem + 131072);        // [2][64][8]
  float* pC       = (float*)(smem + 135168);        // [2][48][8]
  float* sh_q     = (float*)(smem + 138240);        // [512]
  float* sh_sc    = (float*)(smem + 140288);        // [512]
  float* sh_at    = (float*)(smem + 142336);        // [512]
  unsigned* sh_at2= (unsigned*)(smem + 144384);     // [256]
  float* sh_cov   = (float*)(smem + 145408);        // [128]
  float* sh_scl   = (float*)(smem + 145920);        // [128]
  float* sh_gc    = (float*)(smem + 146432);        // [48][8]
  float* sh_h32   = (float*)(smem + 147968);        // [16 i][8 lb]
  float* sh_hv    = (float*)(smem + 148480);        // [8 lb][16 i]
  float* sh_red   = (float*)(smem + 148992);        // [16]

  const int bx = blockIdx.x;
  const int x = bx & 7;        // group (~XCD)
  const int m = bx >> 3;       // member 0..31
  const int b0 = x * 8;
  const int tid = threadIdx.x;
  const int lane = tid & 63;
  const int wv = tid >> 6;

  const int lbB = m >> 2;      // B/ctx role: local batch, quarter
  const int qt = m & 3;
  const int bB = b0 + lbB;

  // ---- preload weight slices into LDS ----
  {
    const uint4* s1 = (const uint4*)(wqhA + (size_t)m * 8192);
    uint4* d1 = (uint4*)wa;
    for (int i = tid; i < 4096; i += 512) d1[i] = s1[i];
    const uint4* s2 = (const uint4*)(wicC + (size_t)m * 6144);
    uint4* d2 = (uint4*)wc;
    for (int i = tid; i < 3072; i += 512) d2[i] = s2[i];
  }
  // ---- local state init ----
  if (tid < 128) {
    int i = tid & 15, lb = tid >> 4;
    sh_h32[i * 8 + lb] = state[(b0 + lb) * H_ + 16 * m + i];
    sh_cov[tid] = 0.f;
  }
  float mymask = (tid < 128) ? vmask[bB * N_ + 128 * qt + tid] : 0.f;

  // A-post mapping (thread = (c, lb))
  const int Ac = tid & 63, Alb = tid >> 6;
  float Abias = 0.f;
  unsigned* Adst;
  {
    int Acol = 64 * m + Ac;
    if (Acol < 512) {
      Adst = pay_q + (b0 + Alb) * 512 + Acol;
    } else {
      int ghcol = Acol - 512;
      Abias = b_hh[ghcol];
      Adst = pay_gh3 + (b0 + Alb) * G3 + 3 * (ghcol & 511) + (ghcol >> 9);
    }
  }
  // hoisted B-phase constants
  float wc8[8], va8[8];
  {
    float4 a0 = *(const float4*)(w_cov + lane * 8);
    float4 a1 = *(const float4*)(w_cov + lane * 8 + 4);
    wc8[0] = a0.x; wc8[1] = a0.y; wc8[2] = a0.z; wc8[3] = a0.w;
    wc8[4] = a1.x; wc8[5] = a1.y; wc8[6] = a1.z; wc8[7] = a1.w;
    float4 b1 = *(const float4*)(v_attn + lane * 8);
    float4 b2 = *(const float4*)(v_attn + lane * 8 + 4);
    va8[0] = b1.x; va8[1] = b1.y; va8[2] = b1.z; va8[3] = b1.w;
    va8[4] = b2.x; va8[5] = b2.y; va8[6] = b2.z; va8[7] = b2.w;
  }
  const __half* vkb = vk + ((size_t)bB * N_ + 128 * qt) * H_;
  const unsigned* epg = ep + x * 32;
  unsigned* myep = ep + x * 32 + m;
  __syncthreads();

  for (int t = 0; t < L; ++t) {
    unsigned e0 = 4u * (unsigned)t;
    // ===== pre-A: wait all 32 members' h-posts of prev step =====
    if (tid < 32) wait_flag(&epg[tid], e0);
    __syncthreads();
    // stage h (8 batches) as [k2p][lb][2]
    for (int i = tid; i < 2048; i += 512) {
      int lb = i >> 8, k2 = i & 255;
      hA[((k2 >> 1) * 8 + lb) * 2 + (k2 & 1)] =
          ld_pay(&pay_h[(b0 + lb) * 256 + k2]);
    }
    __syncthreads();
    // ===== Phase A: 64 cols x 8 batches, dual-batch waves =====
    {
      int p = wv & 3, kh = wv >> 2;
      int lb0 = 2 * p, lb1 = lb0 + 1;
      float a00 = 0.f, a01 = 0.f;
#pragma unroll 8
      for (int i = 0; i < 64; ++i) {
        int k2p = kh * 64 + i;
        uint2 w = wa[k2p * 64 + lane];
        uint2 h0 = *(const uint2*)&hA[(k2p * 8 + lb0) * 2];
        uint2 h1 = *(const uint2*)&hA[(k2p * 8 + lb1) * 2];
        a00 = dot2f(w.x, h0.x, a00); a00 = dot2f(w.y, h0.y, a00);
        a01 = dot2f(w.x, h1.x, a01); a01 = dot2f(w.y, h1.y, a01);
      }
      pA[kh * 512 + lane * 8 + lb0] = a00;
      pA[kh * 512 + lane * 8 + lb1] = a01;
    }
    __syncthreads();
    st_pay(Adst, __float_as_uint(pA[Ac * 8 + Alb] + pA[512 + Ac * 8 + Alb] +
                                 Abias));
    drain_stores();
    __syncthreads();
    if (tid == 0)
      __hip_atomic_store(myep, e0 + 1u, __ATOMIC_RELAXED,
                         __HIP_MEMORY_SCOPE_AGENT);

    // ===== pre-B: wait q producers (members 0..7) =====
    if (tid < 8) wait_flag(&epg[tid], e0 + 1u);
    __syncthreads();
    sh_q[tid] = __uint_as_float(ld_pay(&pay_q[bB * 512 + tid]));
    __syncthreads();
    // ===== Phase B: scores for rows [128qt..128qt+128) of batch bB =====
    {
      float q8[8];
#pragma unroll
      for (int k = 0; k < 8; ++k) q8[k] = sh_q[lane * 8 + k];
      for (int r = 0; r < 16; ++r) {
        int nl = wv * 16 + r;
        float cv = sh_cov[nl];
        float4 raw = *(const float4*)(vkb + (size_t)nl * H_ + lane * 8);
        const __half2* hp = (const __half2*)&raw;
        float p = 0.f;
#pragma unroll
        for (int k = 0; k < 4; ++k) {
          float2 f = __half22float2(hp[k]);
          float e1 = fmaf(cv, wc8[2 * k], q8[2 * k]) + f.x;
          float e2 = fmaf(cv, wc8[2 * k + 1], q8[2 * k + 1]) + f.y;
          p = fmaf(fmaxf(e1, 0.f), va8[2 * k], p);
          p = fmaf(fmaxf(e2, 0.f), va8[2 * k + 1], p);
        }
#pragma unroll
        for (int off = 32; off; off >>= 1) p += __shfl_xor(p, off);
        if (lane == 0) sh_scl[nl] = p;
      }
    }
    __syncthreads();
    if (tid < 128)
      st_pay(&pay_sc[bB * 512 + 128 * qt + tid],
             __float_as_uint(mymask > 0.f ? sh_scl[tid] : NEG));
    drain_stores();
    __syncthreads();
    if (tid == 0)
      __hip_atomic_store(myep, e0 + 2u, __ATOMIC_RELAXED,
                         __HIP_MEMORY_SCOPE_AGENT);

    // ===== pre-softmax: wait my batch's 4 quarter WGs =====
    if (tid < 4) wait_flag(&epg[(m & ~3) + tid], e0 + 2u);
    __syncthreads();
    sh_sc[tid] = __uint_as_float(ld_pay(&pay_sc[bB * 512 + tid]));
    __syncthreads();
    // softmax over 512 (redundant x4 per batch)
    {
      float sv = sh_sc[tid];
      float mx = sv;
#pragma unroll
      for (int off = 32; off; off >>= 1) mx = fmaxf(mx, __shfl_xor(mx, off));
      if (lane == 0) sh_red[wv] = mx;
      __syncthreads();
      mx = sh_red[0];
#pragma unroll
      for (int k = 1; k < 8; ++k) mx = fmaxf(mx, sh_red[k]);
      float pp = expf(sv - mx);
      float ss = pp;
#pragma unroll
      for (int off = 32; off; off >>= 1) ss += __shfl_xor(ss, off);
      if (lane == 0) sh_red[8 + wv] = ss;
      __syncthreads();
      ss = sh_red[8];
#pragma unroll
      for (int k = 1; k < 8; ++k) ss += sh_red[8 + k];
      sh_at[tid] = pp * (1.f / ss);
    }
    __syncthreads();
    if (tid < 256) sh_at2[tid] = f2uh2(sh_at[2 * tid], sh_at[2 * tid + 1]);
    if (tid < 128) {
      float a = sh_at[128 * qt + tid];
      sh_cov[tid] += a;
      attn_out[((size_t)bB * L + t) * N_ + 128 * qt + tid] = a;
    }
    __syncthreads();
    // ===== ctx: h-cols [128qt..128qt+128), dot over all n (fp16) =====
    {
      for (int rr = 0; rr < 16; ++rr) {
        int hc = wv * 16 + rr;
        const __half* vp =
            valT + ((size_t)bB * H_ + 128 * qt + hc) * N_ + lane * 8;
        uint4 u = *(const uint4*)vp;
        uint4 av = *(const uint4*)&sh_at2[lane * 4];
        float acc = 0.f;
        acc = dot2f(u.x, av.x, acc);
        acc = dot2f(u.y, av.y, acc);
        acc = dot2f(u.z, av.z, acc);
        acc = dot2f(u.w, av.w, acc);
#pragma unroll
        for (int off = 32; off; off >>= 1) acc += __shfl_xor(acc, off);
        if (lane == 0) sh_scl[hc] = acc;
      }
    }
    __syncthreads();
    if (tid < 64)
      st_pay(&pay_ctx[bB * 256 + 64 * qt + tid],
             f2uh2(sh_scl[2 * tid], sh_scl[2 * tid + 1]));
    drain_stores();
    __syncthreads();
    if (tid == 0)
      __hip_atomic_store(myep, e0 + 3u, __ATOMIC_RELAXED,
                         __HIP_MEMORY_SCOPE_AGENT);

    // ===== pre-C: wait all 32 (ctx complete for all 8 batches) =====
    if (tid < 32) wait_flag(&epg[tid], e0 + 3u);
    __syncthreads();
    for (int i = tid; i < 2048; i += 512) {
      int lb = i >> 8, k2 = i & 255;
      hC[((k2 >> 1) * 8 + lb) * 2 + (k2 & 1)] =
          ld_pay(&pay_ctx[(b0 + lb) * 256 + k2]);
    }
    __syncthreads();
    // ===== Phase C: 48 gate-cols x 8 batches =====
    {
      int p = wv & 3, kh = wv >> 2;
      int lb0 = 2 * p, lb1 = lb0 + 1;
      float a00 = 0.f, a01 = 0.f;
      if (lane < 48) {
#pragma unroll 8
        for (int i = 0; i < 64; ++i) {
          int k2p = kh * 64 + i;
          uint2 w = wc[k2p * 48 + lane];
          uint2 h0 = *(const uint2*)&hC[(k2p * 8 + lb0) * 2];
          uint2 h1 = *(const uint2*)&hC[(k2p * 8 + lb1) * 2];
          a00 = dot2f(w.x, h0.x, a00); a00 = dot2f(w.y, h0.y, a00);
          a01 = dot2f(w.x, h1.x, a01); a01 = dot2f(w.y, h1.y, a01);
        }
        pC[kh * 384 + lane * 8 + lb0] = a00;
        pC[kh * 384 + lane * 8 + lb1] = a01;
      }
    }
    __syncthreads();
    if (tid < 384) {
      int cc = tid % 48, lb = tid / 48;
      sh_gc[cc * 8 + lb] = pC[cc * 8 + lb] + pC[384 + cc * 8 + lb];
    }
    __syncthreads();
    // ===== GRU pointwise: 16 j x 8 batches =====
    if (tid < 128) {
      int i = tid & 15, lb = tid >> 4;
      int b = b0 + lb;
      int j = 16 * m + i;
      const __half* gp = gie3 + ((size_t)t * B + b) * G3 + 48 * m + 3 * i;
      float gir = __half2float(gp[0]);
      float giz = __half2float(gp[1]);
      float gin = __half2float(gp[2]);
      const unsigned* ghp = pay_gh3 + b * G3 + 48 * m + 3 * i;
      float ghr = __uint_as_float(ld_pay(ghp));
      float ghz = __uint_as_float(ld_pay(ghp + 1));
      float ghn = __uint_as_float(ld_pay(ghp + 2));
      float r = 1.f / (1.f + expf(-(gir + sh_gc[(3 * i) * 8 + lb] + ghr)));
      float z = 1.f / (1.f + expf(-(giz + sh_gc[(3 * i + 1) * 8 + lb] + ghz)));
      float nn = tanhf(gin + sh_gc[(3 * i + 2) * 8 + lb] + r * ghn);
      float hp = sh_h32[i * 8 + lb];
      float hv = (1.f - z) * nn + z * hp;
      sh_h32[i * 8 + lb] = hv;
      sh_hv[lb * 16 + i] = hv;
      out_h[((size_t)b * L + t) * H_ + j] = hv;
    }
    __syncthreads();
    if (tid < 64) {
      int ip = tid & 7, lb = tid >> 3;
      st_pay(&pay_h[(b0 + lb) * 256 + 8 * m + ip],
             f2uh2(sh_hv[lb * 16 + 2 * ip], sh_hv[lb * 16 + 2 * ip + 1]));
    }
    drain_stores();
    __syncthreads();
    if (tid == 0)
      __hip_atomic_store(myep, e0 + 4u, __ATOMIC_RELAXED,
                         __HIP_MEMORY_SCOPE_AGENT);
  }
}

// ---------------- launch ----------------

extern "C" void kernel_launch(void* const* d_in, const int* in_sizes, int n_in,
                              void* d_out, int out_size, void* d_ws, size_t ws_size,
                              hipStream_t stream) {
  const float* emb    = (const float*)d_in[0];
  const float* value  = (const float*)d_in[1];
  const float* vmask  = (const float*)d_in[2];
  const float* state  = (const float*)d_in[3];
  const float* Wq     = (const float*)d_in[4];
  const float* Wk     = (const float*)d_in[5];
  const float* b_attn = (const float*)d_in[6];
  const float* w_cov  = (const float*)d_in[7];
  const float* v_attn = (const float*)d_in[8];
  const float* W_ih   = (const float*)d_in[9];
  const float* W_hh   = (const float*)d_in[10];
  const float* b_ih   = (const float*)d_in[11];
  const float* b_hh   = (const float*)d_in[12];

  float* out = (float*)d_out;
  float* attn_out = out + (size_t)B * L * H_;

  __half* vk_h     = (__half*)d_ws;                           // B*N*H
  __half* valT     = vk_h + (size_t)B * N_ * H_;              // B*H*N
  __half* gie3     = valT + (size_t)B * N_ * H_;              // L*B*G3
  uint2* wqhA      = (uint2*)(gie3 + (size_t)L * B * G3);     // 32*128*64
  uint2* wicC      = wqhA + (size_t)32 * 128 * 64;            // 32*128*48
  unsigned* pay_q  = (unsigned*)(wicC + (size_t)32 * 128 * 48);  // B*512
  unsigned* pay_gh3= pay_q + B * 512;                         // B*1536
  unsigned* pay_sc = pay_gh3 + B * G3;                        // B*512
  unsigned* pay_ctx= pay_sc + B * 512;                        // B*256
  unsigned* pay_h  = pay_ctx + B * 256;                       // B*256
  unsigned* ep     = pay_h + B * 256;                         // 256

  hipFuncSetAttribute((const void*)k_dec,
                      hipFuncAttributeMaxDynamicSharedMemorySize, SMEM_BYTES);

  k_init<<<64, 256, 0, stream>>>(state, pay_h, ep);
  k_cvtT<<<dim3(16, 16, B), 256, 0, stream>>>(value, valT);
  k_wt<<<1024, 256, 0, stream>>>(Wq, W_hh, W_ih, wqhA, wicC);
  k_vk<<<dim3(8, 8, B), 256, 0, stream>>>(value, Wk, b_attn, vk_h);
  k_gie<<<dim3(24, 128), 256, 0, stream>>>(emb, W_ih, b_ih, gie3);

  k_dec<<<256, 512, SMEM_BYTES, stream>>>(
      vk_h, valT, gie3, wqhA, wicC, b_hh, w_cov, v_attn, vmask, state, pay_q,
      pay_gh3, pay_sc, pay_ctx, pay_h, ep, out, attn_out);
}